// Round 12
// baseline (5819.317 us; speedup 1.0000x reference)
//
#include <hip/hip_runtime.h>
#include <math.h>

#define S 512
#define B 64
#define I 1024
#define HD 1024
#define G4 (4*HD)
#define NB 256
#define ARRS 16   // ints per arrival-counter slot (64B line)

typedef _Float16 half8 __attribute__((ext_vector_type(8)));
typedef float floatx4 __attribute__((ext_vector_type(4)));
typedef float f32x4 __attribute__((ext_vector_type(4)));
typedef unsigned uint4v __attribute__((ext_vector_type(4)));
typedef unsigned long long u64x2 __attribute__((ext_vector_type(2)));

// ---------- prep kernels ----------

__global__ void cast_f32_to_f16(const float* __restrict__ src,
                                _Float16* __restrict__ dst, long n8) {
    long i = (long)blockIdx.x * blockDim.x + threadIdx.x;
    if (i >= n8) return;
    const f32x4* s = (const f32x4*)src + i * 2;
    f32x4 a = s[0], b = s[1];
    half8 h;
    h[0] = (_Float16)a[0]; h[1] = (_Float16)a[1];
    h[2] = (_Float16)a[2]; h[3] = (_Float16)a[3];
    h[4] = (_Float16)b[0]; h[5] = (_Float16)b[1];
    h[6] = (_Float16)b[2]; h[7] = (_Float16)b[3];
    *((half8*)dst + i) = h;
}

__global__ void init_state(const float* __restrict__ h0,
                           const float* __restrict__ bi, const float* __restrict__ bh,
                           _Float16* __restrict__ hb0, float* __restrict__ bsum,
                           int* __restrict__ arr, int* __restrict__ xcd_ctr,
                           int* __restrict__ loc) {
    int i = blockIdx.x * blockDim.x + threadIdx.x;
    if (i < B * HD) hb0[i] = (_Float16)h0[i];
    if (i < G4) bsum[i] = bi[i] + bh[i];
    if (i < 32) arr[i * ARRS] = 0;
    if (i < 8) { xcd_ctr[i] = 0; loc[i * 16] = 0; }
}

// ---------- persistent recurrent kernel ----------
// R12 = R11 design with two fault fixes (R10/R11 core dumps):
//  (1) STAGE_HFRAG asm outputs are "=&v" EARLY-CLOBBER -- plain "=v" let the
//      allocator alias an output with a later load's 64-bit address pair ->
//      wild global_load -> HSA fault.
//  (2) LOCAL_POLL has no inline asm: local counter add+poll use the PROVEN
//      agent-scope atomic class (counter at L3); only the bulk DATA goes
//      through the local-L2 sc0 path (that's where the 16x traffic win is).
// 256 blocks x 256 threads, 1 block/CU (128KB LDS) => exactly 32 blocks/XCD.
// Two-level h handoff: L3 exchange + 4KB/block agent-atomic fetch (1MB/step
// chip-wide vs 16MB in R8), republished into per-XCD buffer (plain stores ->
// local L2), staged by the 32 co-XCD blocks via sc0 loads (bypass L1, hit L2).

__global__ __launch_bounds__(256, 1) void lstm_persistent(
    const float*    __restrict__ xf32,
    const _Float16* __restrict__ Wib,
    const _Float16* __restrict__ Whb,
    const float*    __restrict__ bsum,
    const float*    __restrict__ c0,
    _Float16* __restrict__ hr0,
    _Float16* __restrict__ hr1,
    _Float16* __restrict__ hr2,
    float*          __restrict__ out,
    int*            __restrict__ arr,
    int*            __restrict__ xcd_ctr,
    int*            __restrict__ loc,
    _Float16*       __restrict__ xcdbuf)   // 8 XCD x 2 ring x 65536 halves
{
    __shared__ alignas(16) _Float16 fragWh[32768];  // 64 KB
    __shared__ alignas(16) _Float16 hfrag[32768];   // 64 KB
    __shared__ int s_sl;

    const int m = blockIdx.x;
    const int tid = threadIdx.x;
    const int l = tid & 63, w = tid >> 6;
    const int rt = w >> 1, bt = w & 1;

    // ---- XCD self-identification + slot claim ----
    unsigned xcc;
    asm volatile("s_getreg_b32 %0, hwreg(HW_REG_XCC_ID)" : "=s"(xcc));
    xcc &= 7;
    if (tid == 0)
        s_sl = __hip_atomic_fetch_add(&xcd_ctr[xcc], 1, __ATOMIC_RELAXED,
                                      __HIP_MEMORY_SCOPE_AGENT);
    __syncthreads();
    const int sl = s_sl & 31;            // 0..31 within this XCD (clamped)
    const int rg2 = (int)xcc * 16 + (sl >> 1);
    const int bg = sl & 1;
    int* lp = loc + xcc * 16;            // per-XCD counter line (lives at L3)

    // ---- stage Wh fragments into LDS (frag order, conflict-free) ----
    for (int idx = tid; idx < 32 * 128; idx += 256) {
        int r_loc = idx >> 7;
        int ch = idx & 127;
        int rtt = r_loc >> 4, a = r_loc & 15;
        int kstep = ch >> 2, sub = ch & 3;
        int lane = sub * 16 + a;
        int grow = (r_loc & 3) * HD + (rg2 * 8 + (r_loc >> 2));
        int dst = rtt * 16384 + kstep * 512 + lane * 8;
        *(half8*)&fragWh[dst] = *(const half8*)&Whb[(size_t)grow * HD + ch * 8];
    }

    // ---- Wi fragments (may stream from L2; poll-hidden) ----
    uint4v wif[32];
    {
        int a = l & 15;
        int r_loc = rt * 16 + a;
        int grow = (r_loc & 3) * HD + (rg2 * 8 + (r_loc >> 2));
        const _Float16* wrow = Wib + (size_t)grow * I + (l >> 4) * 8;
        #pragma unroll
        for (int kk = 0; kk < 32; ++kk)
            wif[kk] = *(const uint4v*)(wrow + kk * 32);
    }

    const int bq = bg * 32 + bt * 16 + (l & 15);
    const int jq = rg2 * 8 + rt * 4;
    const int j  = jq + (l >> 4);
    const float b0 = bsum[j];
    const float b1 = bsum[HD + j];
    const float b2 = bsum[2 * HD + j];
    const float b3 = bsum[3 * HD + j];
    const size_t cix = (size_t)bq * HD + j;
    float c = c0[cix];

    // fetch/republish indices (fixed per thread)
    const int fb  = 2 * sl + (tid >> 7);       // batch this thread fetches
    const int v7  = tid & 127;
    const int fkk = v7 >> 2, fq = v7 & 3;
    const int fg_ = fb >> 4, fa = fb & 15;
    const int fdst = (fg_ * 2048 + fkk * 64 + fq * 16 + fa) * 8;  // halves

    // x-projection over f32 source with on-the-fly cvt
    #define ACCX_COMPUTE(dstacc, trow)                                          \
    {                                                                           \
        const float* xrow_ = xf32 + ((size_t)(trow) * B + bq) * I + (l >> 4) * 8;\
        floatx4 a_ = {0.f, 0.f, 0.f, 0.f};                                      \
        _Pragma("unroll")                                                       \
        for (int g = 0; g < 4; ++g) {                                           \
            f32x4 xf[8][2];                                                     \
            _Pragma("unroll")                                                   \
            for (int q = 0; q < 8; ++q) {                                       \
                const float* pp = xrow_ + (g * 8 + q) * 32;                     \
                xf[q][0] = *(const f32x4*)pp;                                   \
                xf[q][1] = *(const f32x4*)(pp + 4);                             \
            }                                                                   \
            _Pragma("unroll")                                                   \
            for (int q = 0; q < 8; ++q) {                                       \
                half8 hx;                                                       \
                _Pragma("unroll")                                               \
                for (int e2 = 0; e2 < 4; ++e2) {                                \
                    hx[e2]     = (_Float16)xf[q][0][e2];                        \
                    hx[4 + e2] = (_Float16)xf[q][1][e2];                        \
                }                                                               \
                a_ = __builtin_amdgcn_mfma_f32_16x16x32_f16(                    \
                    __builtin_bit_cast(half8, wif[g * 8 + q]), hx, a_, 0, 0, 0);\
            }                                                                   \
        }                                                                       \
        dstacc = a_;                                                            \
    }

    // ---- prologue: fetch h0 -> republish to xcdbuf ring 0 ----
    {
        _Float16* xslot = xcdbuf + ((size_t)xcc * 2 + 0) * 65536;
        const unsigned long long* sp =
            (const unsigned long long*)hr0 + (size_t)fb * 256 + fkk * 8 + fq * 2;
        unsigned long long q0 = __hip_atomic_load(sp,     __ATOMIC_RELAXED, __HIP_MEMORY_SCOPE_AGENT);
        unsigned long long q1 = __hip_atomic_load(sp + 1, __ATOMIC_RELAXED, __HIP_MEMORY_SCOPE_AGENT);
        u64x2 val; val.x = q0; val.y = q1;
        *(u64x2*)&xslot[fdst] = val;
    }
    asm volatile("s_waitcnt vmcnt(0)" ::: "memory");   // republish visible in L2
    __syncthreads();
    if (tid == 0)
        __hip_atomic_fetch_add(lp, 1, __ATOMIC_RELAXED, __HIP_MEMORY_SCOPE_AGENT);

    // ---- accx(0) while local round completes ----
    floatx4 accx;
    ACCX_COMPUTE(accx, 0)

    // local poll: proven agent-scope atomic load class, no asm
    #define LOCAL_POLL(target)                                                  \
        if (tid == 0) {                                                         \
            while (__hip_atomic_load(lp, __ATOMIC_RELAXED,                      \
                                     __HIP_MEMORY_SCOPE_AGENT) < (target))      \
                __builtin_amdgcn_s_sleep(1);                                    \
        }                                                                       \
        __syncthreads();

    #define STAGE_HFRAG(xslot)                                                  \
    {                                                                           \
        const char* sb = (const char*)((xslot) + (size_t)bg * 32768)            \
                         + (size_t)tid * 16;                                    \
        uint4v o0,o1,o2,o3,o4,o5,o6,o7;                                         \
        asm volatile(                                                           \
            "global_load_dwordx4 %0, %8, off sc0\n\t"                           \
            "global_load_dwordx4 %1, %9, off sc0\n\t"                           \
            "global_load_dwordx4 %2, %10, off sc0\n\t"                          \
            "global_load_dwordx4 %3, %11, off sc0\n\t"                          \
            "global_load_dwordx4 %4, %12, off sc0\n\t"                          \
            "global_load_dwordx4 %5, %13, off sc0\n\t"                          \
            "global_load_dwordx4 %6, %14, off sc0\n\t"                          \
            "global_load_dwordx4 %7, %15, off sc0\n\t"                          \
            "s_waitcnt vmcnt(0)"                                                \
            : "=&v"(o0),"=&v"(o1),"=&v"(o2),"=&v"(o3),                          \
              "=&v"(o4),"=&v"(o5),"=&v"(o6),"=&v"(o7)                           \
            : "v"(sb),"v"(sb+4096),"v"(sb+8192),"v"(sb+12288),                  \
              "v"(sb+16384),"v"(sb+20480),"v"(sb+24576),"v"(sb+28672)           \
            : "memory");                                                        \
        *(uint4v*)&hfrag[((size_t)0*256+tid)*8] = o0;                           \
        *(uint4v*)&hfrag[((size_t)1*256+tid)*8] = o1;                           \
        *(uint4v*)&hfrag[((size_t)2*256+tid)*8] = o2;                           \
        *(uint4v*)&hfrag[((size_t)3*256+tid)*8] = o3;                           \
        *(uint4v*)&hfrag[((size_t)4*256+tid)*8] = o4;                           \
        *(uint4v*)&hfrag[((size_t)5*256+tid)*8] = o5;                           \
        *(uint4v*)&hfrag[((size_t)6*256+tid)*8] = o6;                           \
        *(uint4v*)&hfrag[((size_t)7*256+tid)*8] = o7;                           \
        const char* sc = sb + 32768;                                            \
        asm volatile(                                                           \
            "global_load_dwordx4 %0, %8, off sc0\n\t"                           \
            "global_load_dwordx4 %1, %9, off sc0\n\t"                           \
            "global_load_dwordx4 %2, %10, off sc0\n\t"                          \
            "global_load_dwordx4 %3, %11, off sc0\n\t"                          \
            "global_load_dwordx4 %4, %12, off sc0\n\t"                          \
            "global_load_dwordx4 %5, %13, off sc0\n\t"                          \
            "global_load_dwordx4 %6, %14, off sc0\n\t"                          \
            "global_load_dwordx4 %7, %15, off sc0\n\t"                          \
            "s_waitcnt vmcnt(0)"                                                \
            : "=&v"(o0),"=&v"(o1),"=&v"(o2),"=&v"(o3),                          \
              "=&v"(o4),"=&v"(o5),"=&v"(o6),"=&v"(o7)                           \
            : "v"(sc),"v"(sc+4096),"v"(sc+8192),"v"(sc+12288),                  \
              "v"(sc+16384),"v"(sc+20480),"v"(sc+24576),"v"(sc+28672)           \
            : "memory");                                                        \
        *(uint4v*)&hfrag[((size_t)8*256+tid)*8]  = o0;                          \
        *(uint4v*)&hfrag[((size_t)9*256+tid)*8]  = o1;                          \
        *(uint4v*)&hfrag[((size_t)10*256+tid)*8] = o2;                          \
        *(uint4v*)&hfrag[((size_t)11*256+tid)*8] = o3;                          \
        *(uint4v*)&hfrag[((size_t)12*256+tid)*8] = o4;                          \
        *(uint4v*)&hfrag[((size_t)13*256+tid)*8] = o5;                          \
        *(uint4v*)&hfrag[((size_t)14*256+tid)*8] = o6;                          \
        *(uint4v*)&hfrag[((size_t)15*256+tid)*8] = o7;                          \
    }

    LOCAL_POLL(32)
    STAGE_HFRAG(xcdbuf + (size_t)xcc * 2 * 65536)
    __syncthreads();   // hfrag(h0) ready

    int tm = 0;
    for (int t = 0; t < S; ++t) {
        // ---- h-chain from LDS frags ----
        floatx4 acch = {0.f, 0.f, 0.f, 0.f};
        #pragma unroll
        for (int kk = 0; kk < 32; ++kk) {
            half8 ah  = *(const half8*)&fragWh[rt * 16384 + kk * 512 + l * 8];
            half8 bhv = *(const half8*)&hfrag[(bt * 32 + kk) * 512 + l * 8];
            acch = __builtin_amdgcn_mfma_f32_16x16x32_f16(ah, bhv, acch, 0, 0, 0);
        }

        // ---- gates ----
        float pi = accx[0] + acch[0] + b0;
        float pf = accx[1] + acch[1] + b1;
        float po = accx[2] + acch[2] + b2;
        float pg = accx[3] + acch[3] + b3;

        float ig = 1.f / (1.f + __expf(-pi));
        float fg = 1.f / (1.f + __expf(-pf));
        float og = 1.f / (1.f + __expf(-po));
        float gg = 1.f - 2.f / (__expf(2.f * pg) + 1.f);

        c = c * fg + ig * gg;
        float th = 1.f - 2.f / (__expf(2.f * c) + 1.f);
        float ht = og * th;

        // ---- pack quad (shuffles pre-divergence) ----
        unsigned hb16 = (unsigned)__builtin_bit_cast(unsigned short, (_Float16)ht);
        unsigned p16 = (unsigned)__shfl_xor((int)hb16, 16);
        unsigned pw0 = hb16 | (p16 << 16);
        unsigned long long p32 = (unsigned)__shfl_xor((int)pw0, 32);
        unsigned long long w64 = (unsigned long long)pw0 | (p32 << 32);
        float v1 = __shfl_xor(ht, 16);
        float v2 = __shfl_xor(ht, 32);
        float v3 = __shfl_xor(ht, 48);

        _Float16* hb_w = (tm == 0) ? hr1 : (tm == 1) ? hr2 : hr0;

        if (t == S - 1) {
            if ((l >> 4) == 0) {
                f32x4 o = {ht, v1, v2, v3};
                *(f32x4*)&out[((size_t)t * B + bq) * HD + jq] = o;
            }
            out[(size_t)S * B * HD + cix] = ht;                   // h_f
            out[(size_t)S * B * HD + (size_t)B * HD + cix] = c;   // c_f
            break;
        }

        // ---- RELEASE (R5-proven): exchange -> vmcnt(0) -> sync -> arrive ----
        if ((l >> 4) == 0) {
            unsigned long long* dst =
                (unsigned long long*)hb_w + ((size_t)bq * HD + jq) / 4;
            __hip_atomic_exchange(dst, w64, __ATOMIC_RELAXED,
                                  __HIP_MEMORY_SCOPE_AGENT);
        }
        asm volatile("s_waitcnt vmcnt(0)" ::: "memory");
        __syncthreads();
        if (tid == 0)
            __hip_atomic_fetch_add(arr + (m >> 3) * ARRS, 1,
                                   __ATOMIC_RELAXED, __HIP_MEMORY_SCOPE_AGENT);

        // ---- out store AFTER arrive ----
        if ((l >> 4) == 0) {
            f32x4 o = {ht, v1, v2, v3};
            *(f32x4*)&out[((size_t)t * B + bq) * HD + jq] = o;
        }

        // ---- accx(t+1): f32 loads + cvt + MFMA, overlaps the global wait ----
        floatx4 accx_n;
        ACCX_COMPUTE(accx_n, t + 1)

        // ---- global poll: all 32 arrival lines in parallel ----
        if (w == 0) {
            const int target = 8 * (t + 1);
            int* ap = arr + (l & 31) * ARRS;
            while (!__all(__hip_atomic_load(ap, __ATOMIC_RELAXED,
                                            __HIP_MEMORY_SCOPE_AGENT) >= target))
                __builtin_amdgcn_s_sleep(1);
        }
        __syncthreads();   // h_{t+1} globally visible at L3

        // ---- fetch 4KB from L3 -> republish to local L2 ring ----
        const int rr = (t + 1) & 1;
        _Float16* xslot = xcdbuf + ((size_t)xcc * 2 + rr) * 65536;
        {
            const unsigned long long* sp =
                (const unsigned long long*)hb_w + (size_t)fb * 256 + fkk * 8 + fq * 2;
            unsigned long long q0 = __hip_atomic_load(sp,     __ATOMIC_RELAXED, __HIP_MEMORY_SCOPE_AGENT);
            unsigned long long q1 = __hip_atomic_load(sp + 1, __ATOMIC_RELAXED, __HIP_MEMORY_SCOPE_AGENT);
            u64x2 val; val.x = q0; val.y = q1;
            *(u64x2*)&xslot[fdst] = val;
        }
        asm volatile("s_waitcnt vmcnt(0)" ::: "memory");  // republish in local L2
        __syncthreads();
        if (tid == 0)
            __hip_atomic_fetch_add(lp, 1, __ATOMIC_RELAXED,
                                   __HIP_MEMORY_SCOPE_AGENT);

        // ---- local poll + stage hfrag(h_{t+1}) from local L2 ----
        LOCAL_POLL(32 * (t + 2))
        STAGE_HFRAG(xslot)
        accx = accx_n;
        __syncthreads();   // hfrag ready
        tm = (tm == 2) ? 0 : tm + 1;
    }
}

// ---------- launch ----------

extern "C" void kernel_launch(void* const* d_in, const int* in_sizes, int n_in,
                              void* d_out, int out_size, void* d_ws, size_t ws_size,
                              hipStream_t stream) {
    const float* x  = (const float*)d_in[0];
    const float* h0 = (const float*)d_in[1];
    const float* c0 = (const float*)d_in[2];
    const float* Wi = (const float*)d_in[3];
    const float* bi = (const float*)d_in[4];
    const float* Wh = (const float*)d_in[5];
    const float* bh = (const float*)d_in[6];
    float* out = (float*)d_out;

    char* p = (char*)d_ws;
    _Float16* Wib = (_Float16*)p; p += (size_t)G4 * I * 2;
    _Float16* Whb = (_Float16*)p; p += (size_t)G4 * HD * 2;
    _Float16* hr0 = (_Float16*)p; p += (size_t)B * HD * 2;
    _Float16* hr1 = (_Float16*)p; p += (size_t)B * HD * 2;
    _Float16* hr2 = (_Float16*)p; p += (size_t)B * HD * 2;
    float* bsum   = (float*)p;    p += (size_t)G4 * 4;
    int* arr      = (int*)p;      p += 32 * ARRS * 4;
    int* xcd_ctr  = (int*)p;      p += 64;
    int* loc      = (int*)p;      p += 8 * 16 * 4;
    _Float16* xcdbuf = (_Float16*)p; p += (size_t)8 * 2 * 65536 * 2;

    long nw8 = (long)G4 * I / 8;
    cast_f32_to_f16<<<(int)((nw8 + 255) / 256), 256, 0, stream>>>(Wi, Wib, nw8);
    cast_f32_to_f16<<<(int)((nw8 + 255) / 256), 256, 0, stream>>>(Wh, Whb, nw8);
    init_state<<<(B * HD + 255) / 256, 256, 0, stream>>>(h0, bi, bh, hr0, bsum,
                                                         arr, xcd_ctr, loc);

    const float* xp = x;
    const float* c0p = c0;
    void* args[] = {(void*)&xp, (void*)&Wib, (void*)&Whb, (void*)&bsum,
                    (void*)&c0p, (void*)&hr0, (void*)&hr1, (void*)&hr2,
                    (void*)&out, (void*)&arr, (void*)&xcd_ctr, (void*)&loc,
                    (void*)&xcdbuf};
    hipError_t rc = hipLaunchCooperativeKernel((const void*)lstm_persistent,
                                               dim3(NB), dim3(256), args, 0, stream);
    if (rc != hipSuccess) {
        // Fallback: plain launch. 256 blocks at 1 block/CU (128KB LDS) on a
        // 256-CU chip are fully co-resident; barrier is monotonic.
        lstm_persistent<<<dim3(NB), dim3(256), 0, stream>>>(
            xp, Wib, Whb, bsum, c0p, hr0, hr1, hr2, out, arr, xcd_ctr, loc, xcdbuf);
    }
}